// Round 3
// baseline (230.770 us; speedup 1.0000x reference)
//
#include <hip/hip_runtime.h>

#define CIN    128
#define HH     56
#define WW_    56
#define NBATCH 32
#define COUT   256
#define KTOT   1152          // 9 taps * 128 ci  (k-order: kh, kw, ci)
#define PLANE  3136          // 56*56
#define HP     58            // padded H/W
#define BM     128           // c_out tile
#define BN     128           // pixel tile
#define NSTEP  36            // K steps of 32 ci: 9 taps * 4 quarters

#define WB_OFF   0                         // bf16 weights [256][9][128] in ws
#define XP_OFF   (1u << 20)                // padded bf16 input [32][58][58][128]

#define SLOT 8192                          // A-only slot: 128 rows x 64B (32 ci)

typedef __attribute__((ext_vector_type(8))) short bf16x8;
typedef __attribute__((ext_vector_type(4))) float f32x4;

__device__ __forceinline__ unsigned short f2bf(float f) {
    unsigned int u = __builtin_bit_cast(unsigned int, f);
    u += 0x7fffu + ((u >> 16) & 1u);   // RNE
    return (unsigned short)(u >> 16);
}

__device__ __forceinline__ void gl_lds16(const void* g, void* l) {
    __builtin_amdgcn_global_load_lds(
        (const __attribute__((address_space(1))) void*)g,
        (__attribute__((address_space(3))) void*)l, 16, 0, 0);
}

// ---- pre-pass 1: weights OIHW fp32 -> [o][tap][ci] bf16, coalesced out ----
__global__ __launch_bounds__(256)
void wprep(const float* __restrict__ w, unsigned short* __restrict__ wb) {
    __shared__ __align__(16) unsigned short L[KTOT];
    const int o = blockIdx.x;
    const int t = threadIdx.x;
    const float4* src = (const float4*)(w + (size_t)o * KTOT);   // 288 float4
    #pragma unroll
    for (int e = 0; e < 2; ++e) {
        const int q = t + e * 256;
        if (q < 288) {
            const float4 v = src[q];
            #pragma unroll
            for (int u = 0; u < 4; ++u) {
                const int idx = q * 4 + u;       // = ci*9 + tap
                const int ci  = idx / 9;
                const int tap = idx - ci * 9;
                L[tap * 128 + ci] = f2bf(((const float*)&v)[u]);
            }
        }
    }
    __syncthreads();
    if (t < 144)                                  // 1152 shorts = 144 uint4
        ((uint4*)(wb + (size_t)o * KTOT))[t] = ((const uint4*)L)[t];
}

// ---- pre-pass 2: NCHW fp32 -> padded NHWC bf16 (unchanged, verified) ----
__global__ __launch_bounds__(256)
void xprep(const float* __restrict__ in, unsigned short* __restrict__ xp) {
    const int b  = blockIdx.x;               // n*58 + h_out
    const int n  = b / HP;
    const int ho = b - n * HP;
    const int t  = threadIdx.x;
    uint4* orow = (uint4*)(xp + (((size_t)n * HP + ho) * HP) * CIN);  // 928 uint4 per row

    if (ho == 0 || ho == HP - 1) {
        #pragma unroll
        for (int e = 0; e < 4; ++e) {
            const int idx = t + e * 256;
            if (idx < 928) orow[idx] = (uint4){0u, 0u, 0u, 0u};
        }
        return;
    }

    __shared__ unsigned short L[CIN * 57];   // [ci][w], padded to 57 shorts
    const int h  = ho - 1;
    const int w  = t & 63;
    const int cb = t >> 6;                   // wave id 0..3 -> ci block
    if (w < WW_) {
        const float* ib = in + ((size_t)n * CIN) * PLANE + (size_t)h * WW_ + w;
        #pragma unroll
        for (int e = 0; e < 32; ++e) {
            const int ci = cb * 32 + e;
            L[ci * 57 + w] = f2bf(ib[(size_t)ci * PLANE]);
        }
    }
    __syncthreads();

    #pragma unroll
    for (int e = 0; e < 4; ++e) {
        const int idx = t + e * 256;         // uint4 index within the row
        if (idx < 928) {
            const int wo = idx >> 4;         // pixel 0..57
            const int ch = idx & 15;         // 8-ci chunk
            uint4 pk = {0u, 0u, 0u, 0u};
            if (wo >= 1 && wo <= WW_) {
                const int wi = wo - 1;
                unsigned v[8];
                #pragma unroll
                for (int i = 0; i < 8; ++i)
                    v[i] = L[(ch * 8 + i) * 57 + wi];
                pk.x = v[0] | (v[1] << 16);
                pk.y = v[2] | (v[3] << 16);
                pk.z = v[4] | (v[5] << 16);
                pk.w = v[6] | (v[7] << 16);
            }
            orow[idx] = pk;
        }
    }
}

// ---- main conv: A via 4-slot LDS pipeline (32KB, 3 blocks/CU), B DIRECT
// from global to MFMA operand regs (layout-identical bytes -> bit-identical
// result). Wave = 128 cout x 32 px (1m x 4n): B has zero cross-wave
// redundancy; A's 4x reuse served by LDS. One barrier + one counted
// vmcnt(2) per 32-ci step; stage-ahead 3 slots; B piped 1 step ahead. ----
__global__ __launch_bounds__(256, 3)
void conv_mfma(const unsigned short* __restrict__ wb,
               const unsigned short* __restrict__ xp,
               const float* __restrict__ bias,
               float* __restrict__ out)
{
    __shared__ __align__(16) char lds[4 * SLOT];

    const int t = threadIdx.x;

    // bijective XCD swizzle (1568 % 8 == 0); pairs (2k,2k+1) share pix0
    const int bid0 = blockIdx.x;
    const int bid  = (bid0 & 7) * ((NBATCH * PLANE / BN * 2) >> 3) + (bid0 >> 3);
    const int c0   = (bid & 1) * BM;
    const int pix0 = (bid >> 1) * BN;

    // ---- A staging: linear LDS dest, inverse-swizzled global source.
    // slot = 128 rows x 4 chunks(16B); phys_chunk = logical ^ ((row>>1)&3)
    const char* aSrc[2];
    int aDst[2];
    #pragma unroll
    for (int e = 0; e < 2; ++e) {
        const int idx = t + e * 256;          // 16B unit 0..511
        const int row = idx >> 2;
        const int lc  = (idx & 3) ^ ((idx >> 3) & 3);   // logical ci-chunk
        aSrc[e] = (const char*)wb + (size_t)(c0 + row) * (KTOT * 2) + lc * 16;
        aDst[e] = idx * 16;
    }

    auto stageA = [&](int hi) {               // 2 gl_lds -> slot hi&3
        char* sl = lds + (hi & 3) * SLOT;
        gl_lds16(aSrc[0] + hi * 64, sl + aDst[0]);   // tap*256+q*64 == hi*64
        gl_lds16(aSrc[1] + hi * 64, sl + aDst[1]);
    };

    // ---- B direct-load bases: lane holds pixel (wn + j*16 + lr), 8 ci at
    // chunk quad — exactly xp's NHWC byte layout.
    const int lane = t & 63;
    const int wave = t >> 6;
    const int wn   = wave * 32;               // wave owns 32 pixels
    const int lr   = lane & 15;
    const int quad = lane >> 4;
    const char* bB[2];
    #pragma unroll
    for (int j = 0; j < 2; ++j) {
        const int pix = pix0 + wn + j * 16 + lr;
        const int n   = pix / PLANE;
        const int rem = pix - n * PLANE;
        const int h   = rem / WW_;
        const int w   = rem - h * WW_;
        bB[j] = (const char*)xp + ((size_t)(n * HP + h) * HP + w) * (CIN * 2) + quad * 16;
    }

    auto loadB = [&](int hi, bf16x8 (&bf)[2]) {   // 2 global_load_dwordx4
        const int tap  = hi >> 2;
        const int boff = ((tap / 3) * HP + (tap % 3)) * (CIN * 2) + (hi & 3) * 64;
        bf[0] = *(const bf16x8*)(bB[0] + boff);
        bf[1] = *(const bf16x8*)(bB[1] + boff);
    };

    // ---- A fragment read offsets (swizzle-matched) ----
    const int s = (lr >> 1) & 3;
    int offA[8];
    #pragma unroll
    for (int i = 0; i < 8; ++i) {
        const int row = i * 16 + lr;
        offA[i] = row * 64 + ((quad ^ s) * 16);
    }

    f32x4 acc[8][2];
    #pragma unroll
    for (int i = 0; i < 8; ++i)
        #pragma unroll
        for (int j = 0; j < 2; ++j)
            acc[i][j] = (f32x4){0.f, 0.f, 0.f, 0.f};

    // step hi: {vmcnt(2): A(hi+1) landed, B(hi) landed; barrier; ds_read A(hi);
    // loadB(hi+1); stageA(hi+3); MFMA(hi)}. vmcnt never 0 until the tail.
    auto step = [&](int hi, bf16x8 (&cur)[2], bf16x8 (&nxt)[2]) {
        if (hi + 2 < NSTEP) asm volatile("s_waitcnt vmcnt(2)" ::: "memory");
        else                asm volatile("s_waitcnt vmcnt(0)" ::: "memory");
        __builtin_amdgcn_s_barrier();
        const char* sl = lds + (hi & 3) * SLOT;
        bf16x8 afr[8];
        #pragma unroll
        for (int i = 0; i < 8; ++i)
            afr[i] = *(const bf16x8*)(sl + offA[i]);
        if (hi + 1 < NSTEP) loadB(hi + 1, nxt);
        if (hi + 3 < NSTEP) stageA(hi + 3);
        __builtin_amdgcn_s_setprio(1);
        #pragma unroll
        for (int i = 0; i < 8; ++i)
            #pragma unroll
            for (int j = 0; j < 2; ++j)
                acc[i][j] = __builtin_amdgcn_mfma_f32_16x16x32_bf16(afr[i], cur[j], acc[i][j], 0, 0, 0);
        __builtin_amdgcn_s_setprio(0);
    };

    // prologue issue order (vmcnt accounting): A0(2) A1(2) B0(2) A2(2)
    bf16x8 b0[2], b1[2];
    stageA(0); stageA(1);
    loadB(0, b0);
    stageA(2);

    for (int h2 = 0; h2 < NSTEP; h2 += 2) {   // static ping-pong (rule #20)
        step(h2,     b0, b1);
        step(h2 + 1, b1, b0);
    }

    // ---- epilogue ----
    #pragma unroll
    for (int j = 0; j < 2; ++j) {
        const int pg    = pix0 + wn + j * 16 + lr;
        const int ni    = pg / PLANE;
        const int inner = pg - ni * PLANE;
        float* op = out + (size_t)ni * (COUT * PLANE) + inner;
        #pragma unroll
        for (int i = 0; i < 8; ++i) {
            const int crow = c0 + i * 16 + quad * 4;
            #pragma unroll
            for (int r = 0; r < 4; ++r)
                op[(size_t)(crow + r) * PLANE] = acc[i][j][r] + bias[crow + r];
        }
    }
}

extern "C" void kernel_launch(void* const* d_in, const int* in_sizes, int n_in,
                              void* d_out, int out_size, void* d_ws, size_t ws_size,
                              hipStream_t stream) {
    const float* in   = (const float*)d_in[0];
    const float* wt   = (const float*)d_in[1];
    const float* bias = (const float*)d_in[2];
    float* out        = (float*)d_out;

    unsigned short* wbuf = (unsigned short*)((char*)d_ws + WB_OFF);
    unsigned short* xpb  = (unsigned short*)((char*)d_ws + XP_OFF);

    wprep<<<COUT, 256, 0, stream>>>(wt, wbuf);
    xprep<<<NBATCH * HP, 256, 0, stream>>>(in, xpb);

    conv_mfma<<<dim3((NBATCH * PLANE / BN) * 2), 256, 0, stream>>>(wbuf, xpb, bias, out);
}

// Round 4
// 203.254 us; speedup vs baseline: 1.1354x; 1.1354x over previous
//
#include <hip/hip_runtime.h>

#define CIN    128
#define HH     56
#define WW_    56
#define NBATCH 32
#define COUT   256
#define KTOT   1152          // 9 taps * 128 ci  (k-order: kh, kw, ci)
#define PLANE  3136          // 56*56
#define HP     58            // padded H/W
#define BM     128           // c_out tile
#define BN     128           // pixel tile
#define BK     64            // k per step (always within one tap: 1152 = 9*128)
#define NXROWS (NBATCH * HP) // 1856 x-prep blocks

#define WB_OFF   0                         // bf16 weights [256][9][128] in ws
#define XP_OFF   (1u << 20)                // padded bf16 input [32][58][58][128]

typedef __attribute__((ext_vector_type(8))) short bf16x8;
typedef __attribute__((ext_vector_type(4))) float f32x4;

__device__ __forceinline__ unsigned short f2bf(float f) {
    unsigned int u = __builtin_bit_cast(unsigned int, f);
    u += 0x7fffu + ((u >> 16) & 1u);   // RNE
    return (unsigned short)(u >> 16);
}

__device__ __forceinline__ void gl_lds16(const void* g, void* l) {
    __builtin_amdgcn_global_load_lds(
        (const __attribute__((address_space(1))) void*)g,
        (__attribute__((address_space(3))) void*)l, 16, 0, 0);
}

// ---- fused pre-pass: blocks [0,1856) convert input NCHW fp32 -> padded NHWC
// bf16; blocks [1856,2112) convert weights OIHW fp32 -> [o][tap][ci] bf16.
// x-path v2 (G13): float4 global reads (all 256 lanes), LDS [ci/8][w][ci%8]
// so each output uint4 is ONE aligned ds_read_b128 (2-way banks = free),
// replacing 8 scalar LDS reads + bit-packing. Same f2bf -> bit-identical xp.
__global__ __launch_bounds__(256)
void prep(const float* __restrict__ in, const float* __restrict__ w,
          unsigned short* __restrict__ xp, unsigned short* __restrict__ wb) {
    __shared__ __align__(16) unsigned short Lx[16 * 456];   // 14592 B
    __shared__ __align__(16) unsigned short Lw[KTOT];       //  2304 B

    const int b = blockIdx.x;
    const int t = threadIdx.x;

    if (b >= NXROWS) {
        // ---- weight path ----
        const int o = b - NXROWS;
        const float4* src = (const float4*)(w + (size_t)o * KTOT);   // 288 float4
        #pragma unroll
        for (int e = 0; e < 2; ++e) {
            const int q = t + e * 256;
            if (q < 288) {
                const float4 v = src[q];
                #pragma unroll
                for (int u = 0; u < 4; ++u) {
                    const int idx = q * 4 + u;       // = ci*9 + tap
                    const int ci  = idx / 9;
                    const int tap = idx - ci * 9;
                    Lw[tap * 128 + ci] = f2bf(((const float*)&v)[u]);
                }
            }
        }
        __syncthreads();
        if (t < 144)                                  // 1152 shorts = 144 uint4
            ((uint4*)(wb + (size_t)o * KTOT))[t] = ((const uint4*)Lw)[t];
        return;
    }

    // ---- input path: one padded row (n, ho) ----
    const int n  = b / HP;
    const int ho = b - n * HP;
    uint4* orow = (uint4*)(xp + (((size_t)n * HP + ho) * HP) * CIN);  // 928 uint4

    if (ho == 0 || ho == HP - 1) {
        #pragma unroll
        for (int e = 0; e < 4; ++e) {
            const int idx = t + e * 256;
            if (idx < 928) orow[idx] = (uint4){0u, 0u, 0u, 0u};
        }
        return;
    }

    const int h = ho - 1;
    {
        const int ci = t >> 1;                       // 0..127
        const int w0 = (t & 1) * 28;                 // two half-rows
        const float4* ib = (const float4*)(in + ((size_t)n * CIN + ci) * PLANE
                                              + (size_t)h * WW_ + w0);
        unsigned short* Lp = &Lx[(ci >> 3) * 456 + w0 * 8 + (ci & 7)];
        #pragma unroll
        for (int q = 0; q < 7; ++q) {                // 7 x float4 = 28 floats
            const float4 v = ib[q];
            Lp[(q * 4 + 0) * 8] = f2bf(v.x);
            Lp[(q * 4 + 1) * 8] = f2bf(v.y);
            Lp[(q * 4 + 2) * 8] = f2bf(v.z);
            Lp[(q * 4 + 3) * 8] = f2bf(v.w);
        }
    }
    __syncthreads();

    #pragma unroll
    for (int e = 0; e < 4; ++e) {
        const int idx = t + e * 256;                 // uint4 index within row
        if (idx < 928) {
            const int wo = idx >> 4;                 // pixel 0..57
            const int ch = idx & 15;                 // 8-ci chunk
            uint4 pk = (uint4){0u, 0u, 0u, 0u};
            if (wo >= 1 && wo <= WW_)
                pk = *(const uint4*)&Lx[ch * 456 + (wo - 1) * 8];  // 16B-aligned
            orow[idx] = pk;
        }
    }
}

// ---- main: implicit-GEMM conv (round-0 verified kernel, 76.5 us, untouched) ----
__global__ __launch_bounds__(256, 2)
void conv_mfma(const unsigned short* __restrict__ wb,
               const unsigned short* __restrict__ xp,
               const float* __restrict__ bias,
               float* __restrict__ out)
{
    __shared__ __align__(16) unsigned short Asm_[BM * BK];  // 16 KB, rows of 128B
    __shared__ __align__(16) unsigned short Bsm_[BN * BK];  // 16 KB

    const int t    = threadIdx.x;
    const int pix0 = blockIdx.x * BN;
    const int c0   = blockIdx.y * BM;

    const int slot = t & 7;
    const int r32  = t >> 3;                 // 0..31
    const int swiz = (slot ^ (r32 & 7)) * 16;

    const char* aBase = (const char*)wb + (size_t)(c0 + r32) * (KTOT * 2) + swiz;
    const char* bBase[4];
    #pragma unroll
    for (int p = 0; p < 4; ++p) {
        const int pix = pix0 + r32 + p * 32;
        const int n   = pix / PLANE;
        const int rem = pix - n * PLANE;
        const int h   = rem / WW_;
        const int w   = rem - h * WW_;
        bBase[p] = (const char*)xp + ((size_t)(n * HP + h) * HP + w) * (CIN * 2) + swiz;
    }

    const int lane = t & 63;
    const int wave = t >> 6;
    const int wm   = (wave & 1) * 64;
    const int wn   = (wave >> 1) * 64;
    const int lr   = lane & 15;
    const int quad = lane >> 4;
    const int rmod = lr & 7;

    f32x4 acc[4][4];
    #pragma unroll
    for (int i = 0; i < 4; ++i)
        #pragma unroll
        for (int j = 0; j < 4; ++j)
            acc[i][j] = (f32x4){0.f, 0.f, 0.f, 0.f};

    char* const asmb = (char*)Asm_;
    char* const bsmb = (char*)Bsm_;

    for (int tap = 0; tap < 9; ++tap) {
        const int toff = ((tap / 3) * HP + (tap % 3)) * (CIN * 2);
        for (int ci0b = 0; ci0b < 256; ci0b += 128) {
            const int abyte = tap * 256 + ci0b;
            #pragma unroll
            for (int p = 0; p < 4; ++p)
                gl_lds16(aBase + (size_t)p * 32 * (KTOT * 2) + abyte, asmb + p * 4096 + t * 16);
            #pragma unroll
            for (int p = 0; p < 4; ++p)
                gl_lds16(bBase[p] + toff + ci0b, bsmb + p * 4096 + t * 16);
            __syncthreads();

            #pragma unroll
            for (int kk = 0; kk < 2; ++kk) {
                bf16x8 af[4], bfr[4];
                #pragma unroll
                for (int i = 0; i < 4; ++i) {
                    const int r = wm + i * 16 + lr;
                    const int phys = ((kk * 4 + quad) ^ rmod) * 16;
                    af[i] = *(const bf16x8*)(asmb + r * 128 + phys);
                }
                #pragma unroll
                for (int j = 0; j < 4; ++j) {
                    const int r = wn + j * 16 + lr;
                    const int phys = ((kk * 4 + quad) ^ rmod) * 16;
                    bfr[j] = *(const bf16x8*)(bsmb + r * 128 + phys);
                }
                #pragma unroll
                for (int i = 0; i < 4; ++i)
                    #pragma unroll
                    for (int j = 0; j < 4; ++j)
                        acc[i][j] = __builtin_amdgcn_mfma_f32_16x16x32_bf16(af[i], bfr[j], acc[i][j], 0, 0, 0);
            }
            __syncthreads();
        }
    }

    #pragma unroll
    for (int j = 0; j < 4; ++j) {
        const int pg    = pix0 + wn + j * 16 + lr;
        const int ni    = pg / PLANE;
        const int inner = pg - ni * PLANE;
        float* op = out + (size_t)ni * (COUT * PLANE) + inner;
        #pragma unroll
        for (int i = 0; i < 4; ++i) {
            const int crow = c0 + wm + i * 16 + quad * 4;
            #pragma unroll
            for (int r = 0; r < 4; ++r)
                op[(size_t)(crow + r) * PLANE] = acc[i][j][r] + bias[crow + r];
        }
    }
}

extern "C" void kernel_launch(void* const* d_in, const int* in_sizes, int n_in,
                              void* d_out, int out_size, void* d_ws, size_t ws_size,
                              hipStream_t stream) {
    const float* in   = (const float*)d_in[0];
    const float* wt   = (const float*)d_in[1];
    const float* bias = (const float*)d_in[2];
    float* out        = (float*)d_out;

    unsigned short* wb = (unsigned short*)((char*)d_ws + WB_OFF);
    unsigned short* xp = (unsigned short*)((char*)d_ws + XP_OFF);

    prep<<<NXROWS + COUT, 256, 0, stream>>>(in, wt, xp, wb);

    dim3 grid((NBATCH * PLANE) / BN, COUT / BM);
    conv_mfma<<<grid, 256, 0, stream>>>(wb, xp, bias, out);
}